// Round 6
// baseline (343.356 us; speedup 1.0000x reference)
//
#include <hip/hip_runtime.h>

// PConvLinear: B=2, N=60000, K=16, C_in=64, C_add=3, C_mid=16.
// Persistent-block fused pipeline (round 6):
//   250 blocks (1/CU) x 512 thr, 15 tiles of 32 points each (exactly 3750).
//   LWh in REGISTERS for real this time: amdgpu_waves_per_eu(2,2) raises the
//   allocator budget to 256 VGPR so bfr[34] (136 VGPR) stays resident
//   (round 5 compiled to 128 VGPR -> compiler was re-loading LWh every tile).
//   inds prefetched TWO tiles ahead; addF joins the gather (issued a full
//   tile before consumption). One barrier per tile, double-buffered sP.
#define NPTS  60000
#define NBLK  1875          // 32-pt tiles per batch
#define FP    1088          // F padded to 34*32
#define PSTR  1096          // sP row stride (f16)
#define HALF  (32 * PSTR)   // f16 elems per sP buffer
#define SPBYTES    (2 * HALF * 2)      // 140,288 B
#define SPBYTES_FB (32 * PSTR * 2)     // 70,144 B (fallback)
#define LWH_BYTES   (128 * FP * 2)     // 278,528 B
#define INF16_BYTES (2 * NPTS * 64 * 2)
#define WS_NEED     (LWH_BYTES + INF16_BYTES)
#define TILES   15
#define NBLOCKS 250

typedef _Float16 f16x4 __attribute__((ext_vector_type(4)));
typedef _Float16 f16x8 __attribute__((ext_vector_type(8)));
typedef float    f32x4 __attribute__((ext_vector_type(4)));

// ---- pre-kernel: linear_weight fp32 [128][1072] -> f16 LWh2[ch=34][o=128][e=32]
__global__ void __launch_bounds__(256)
cvt_lw_kernel(const float* __restrict__ LW, _Float16* __restrict__ LWh) {
    const int o = blockIdx.x;
    for (int f = threadIdx.x; f < FP; f += 256) {
        const float v = (f < 1072) ? LW[o * 1072 + f] : 0.f;
        LWh[(f >> 5) * (128 * 32) + o * 32 + (f & 31)] = (_Float16)v;
    }
}

// ---- pre-kernel: inF fp32 [2N][64] -> f16 lane-packed: c=ct*16+ml at slot ml*4+ct
__global__ void __launch_bounds__(256)
cvt_inf_kernel(const float* __restrict__ inF, _Float16* __restrict__ inF16) {
    const int tid = blockIdx.x * 256 + threadIdx.x;
    if (tid >= 2 * NPTS * 64) return;
    const int c = tid & 63;
    const int n = tid >> 6;
    inF16[(n << 6) + ((c & 15) << 2) + (c >> 4)] = (_Float16)inF[tid];
}

struct GR { f16x4 fv[4]; float wv[4]; float av[4]; };  // 16 VGPR in flight/point

static __device__ __forceinline__ void issue_gather16(
    const _Float16* __restrict__ inF16, const float* __restrict__ Wn,
    const float* __restrict__ addF, int bbase, int base_nk,
    int ind_lane, int i, int q, int ml, bool mlo, GR& g)
{
    #pragma unroll
    for (int j = 0; j < 4; ++j) {
        const int k   = q * 4 + j;
        const int idx = __shfl(ind_lane, i * 16 + k, 64);   // ds_bpermute
        g.fv[j] = *(const f16x4*)(inF16 + (bbase + idx) * 64 + ml * 4); // 8B
        g.wv[j] = Wn[(base_nk + k) * 16 + ml];
        g.av[j] = mlo ? addF[(base_nk + k) * 3 + ml] : 0.f;
    }
}

// D[row=m=q*4+r][col=c=ml]; f = c*16+m -> d[0..3] CONSECUTIVE f (one b64 write).
// 8B slot swizzle qsw = q ^ (((ml>>2)&1)<<1).
static __device__ __forceinline__ void compute_point(
    const GR& g, _Float16* sProw, int qsw, int ml, bool mlo)
{
    const f32x4 z4 = {0.f, 0.f, 0.f, 0.f};
    f16x4 aW, bA;
    #pragma unroll
    for (int j = 0; j < 4; ++j) { aW[j] = (_Float16)g.wv[j]; bA[j] = (_Float16)g.av[j]; }

    #pragma unroll
    for (int ct = 0; ct < 4; ++ct) {
        f16x4 bF;
        #pragma unroll
        for (int j = 0; j < 4; ++j) bF[j] = g.fv[j][ct];
        const f32x4 d = __builtin_amdgcn_mfma_f32_16x16x16f16(aW, bF, z4, 0, 0, 0);
        f16x4 dh;
        #pragma unroll
        for (int r = 0; r < 4; ++r) dh[r] = (_Float16)d[r];
        *(f16x4*)&sProw[(ct * 16 + ml) * 16 + qsw * 4] = dh;
    }
    const f32x4 d = __builtin_amdgcn_mfma_f32_16x16x16f16(aW, bA, z4, 0, 0, 0);
    if (mlo) {     // c-tile 4: c=64..66, rows unswizzled (qsw==q for ml<3)
        f16x4 dh;
        #pragma unroll
        for (int r = 0; r < 4; ++r) dh[r] = (_Float16)d[r];
        *(f16x4*)&sProw[(64 + ml) * 16 + qsw * 4] = dh;
    }
}

__global__ void __launch_bounds__(512)
__attribute__((amdgpu_waves_per_eu(2, 2)))
pconv_persistent(const _Float16* __restrict__ inF16, // lane-packed f16 (d_ws)
                 const int*   __restrict__ inds,     // [2][60000][16]
                 const float* __restrict__ Wn,       // [2][60000][16][16]
                 const float* __restrict__ addF,     // [2][60000][16][3]
                 const _Float16* __restrict__ LWh,   // LWh2[34][128][32] (d_ws)
                 const float* __restrict__ bias,     // [128]
                 float*       __restrict__ out)      // [2][60000][128]
{
    extern __shared__ __align__(16) _Float16 sP[];   // [2][32][PSTR]

    const int t    = threadIdx.x;
    const int lane = t & 63;
    const int w    = t >> 6;        // wave 0..7
    const int q    = lane >> 4;
    const int ml   = lane & 15;
    const bool mlo = (ml < 3);
    const int qsw  = q ^ (((ml >> 2) & 1) << 1);

    // zero pad cols f in [1072,1088) of BOTH buffers once (never overwritten)
    sP[(t >> 4) * PSTR + 1072 + (t & 15)] = (_Float16)0.f;
    sP[HALF + (t >> 4) * PSTR + 1072 + (t & 15)] = (_Float16)0.f;

    // ---- prologue: per-wave LWh o-slice into registers (34 x f16x8 = 136 VGPR)
    const int o0 = w * 16;
    const _Float16* bPw = LWh + (o0 + ml) * 32 + q * 8;
    f16x8 bfr[34];
    #pragma unroll
    for (int ch = 0; ch < 34; ++ch)
        bfr[ch] = *(const f16x8*)(bPw + ch * 4096);
    const float bz = bias[o0 + ml];

    // ---- tile meta helper
    int gt = blockIdx.x * TILES;
    auto meta = [&](int g, int& bb, int& n0, int& nk) {
        const int b = g / NBLK;
        n0 = (g - b * NBLK) * 32;
        bb = b * NPTS;
        nk = (bb + n0 + w * 4) * 16;
    };

    // ---- tile 0: gathers issued now
    int bbC, n0C, nkC;
    meta(gt, bbC, n0C, nkC);
    GR g0, g1, g2, g3;
    {
        const int ind0 = inds[nkC + lane];
        issue_gather16(inF16, Wn, addF, bbC, nkC,      ind0, 0, q, ml, mlo, g0);
        issue_gather16(inF16, Wn, addF, bbC, nkC + 16, ind0, 1, q, ml, mlo, g1);
        issue_gather16(inF16, Wn, addF, bbC, nkC + 32, ind0, 2, q, ml, mlo, g2);
        issue_gather16(inF16, Wn, addF, bbC, nkC + 48, ind0, 3, q, ml, mlo, g3);
    }
    // ---- tile 1 meta + ind preloaded (full-tile cover)
    int bbN = 0, n0N = 0, nkN = 0, indN = 0;
    if (TILES > 1) { meta(gt + 1, bbN, n0N, nkN); indN = inds[nkN + lane]; }

    for (int tt = 0; tt < TILES; ++tt) {
        const bool more  = (tt + 1 < TILES);
        const bool more2 = (tt + 2 < TILES);
        // prefetch ind for tile tt+2 (consumed next iteration, full-tile cover)
        int bbN2 = 0, n0N2 = 0, nkN2 = 0, indN2 = 0;
        if (more2) { meta(gt + 2, bbN2, n0N2, nkN2); indN2 = inds[nkN2 + lane]; }

        _Float16* sPc = sP + (tt & 1) * HALF;
        _Float16* sPw = sPc + (w * 4) * PSTR;

        // ---- Phase A: consume tile tt, refill gathers for tile tt+1
        compute_point(g0, sPw,            qsw, ml, mlo);
        compute_point(g1, sPw + PSTR,     qsw, ml, mlo);
        if (more) {
            issue_gather16(inF16, Wn, addF, bbN, nkN,      indN, 0, q, ml, mlo, g0);
            issue_gather16(inF16, Wn, addF, bbN, nkN + 16, indN, 1, q, ml, mlo, g1);
        }
        compute_point(g2, sPw + 2 * PSTR, qsw, ml, mlo);
        compute_point(g3, sPw + 3 * PSTR, qsw, ml, mlo);
        if (more) {
            issue_gather16(inF16, Wn, addF, bbN, nkN + 32, indN, 2, q, ml, mlo, g2);
            issue_gather16(inF16, Wn, addF, bbN, nkN + 48, indN, 3, q, ml, mlo, g3);
        }
        __syncthreads();   // sP[tt&1] complete; also fences prev-tile readers

        // ---- Phase B: out[32 x 128] = sP @ (reg-resident LWh^T), no VMEM
        // swizzle read: f16x8 at f=ch*32+q*8 sits at row*PSTR + ch*32
        //               + (q>>1)*16 + ((q&1)^((ch>>1)&1))*8
        f32x4 acc0 = {0.f, 0.f, 0.f, 0.f};
        f32x4 acc1 = {0.f, 0.f, 0.f, 0.f};
        const _Float16* aP0 = sPc + ml * PSTR + (q >> 1) * 16 + (q & 1) * 8;
        const _Float16* aP1 = aP0 + 16 * PSTR;
        const int flip = (q & 1) ? -8 : 8;
        #pragma unroll
        for (int ch = 0; ch < 34; ++ch) {
            const int off = ch * 32 + ((ch & 2) ? flip : 0);
            f16x8 a0 = *(const f16x8*)(aP0 + off);     // ds_read_b128
            f16x8 a1 = *(const f16x8*)(aP1 + off);
            acc0 = __builtin_amdgcn_mfma_f32_16x16x32_f16(a0, bfr[ch], acc0, 0, 0, 0);
            acc1 = __builtin_amdgcn_mfma_f32_16x16x32_f16(a1, bfr[ch], acc1, 0, 0, 0);
        }

        // ---- epilogue: bias + store (rows q*4+r and +16, cols o0+ml)
        float* ob = out + (bbC + n0C + q * 4) * 128 + o0 + ml;
        #pragma unroll
        for (int r = 0; r < 4; ++r)
            ob[r * 128] = acc0[r] + bz;
        ob += 16 * 128;
        #pragma unroll
        for (int r = 0; r < 4; ++r)
            ob[r * 128] = acc1[r] + bz;

        bbC = bbN; n0C = n0N;
        bbN = bbN2; n0N = n0N2; nkN = nkN2; indN = indN2;
        ++gt;
    }
}

// ================= fallback (ws too small): round-4 fp32-gather kernel =========
struct GR32 { float fv[4][4]; float wv[4]; float av[4]; };

static __device__ __forceinline__ void issue_gather32(
    const float* __restrict__ inF, const float* __restrict__ Wn,
    const float* __restrict__ addF, int bbase, int base_nk,
    int ind_lane, int i, int q, int ml, bool mlo, GR32& g)
{
    #pragma unroll
    for (int j = 0; j < 4; ++j) {
        const int k   = q * 4 + j;
        const int idx = __shfl(ind_lane, i * 16 + k, 64);
        const float* fp = inF + (bbase + idx) * 64 + ml;
        #pragma unroll
        for (int ct = 0; ct < 4; ++ct)
            g.fv[ct][j] = fp[ct * 16];
        g.wv[j] = Wn[(base_nk + k) * 16 + ml];
        g.av[j] = mlo ? addF[(base_nk + k) * 3 + ml] : 0.f;
    }
}

static __device__ __forceinline__ void compute_point32(
    const GR32& g, _Float16* sProw, int qsw, int ml, bool mlo)
{
    const f32x4 z4 = {0.f, 0.f, 0.f, 0.f};
    f16x4 aW, bA;
    #pragma unroll
    for (int j = 0; j < 4; ++j) { aW[j] = (_Float16)g.wv[j]; bA[j] = (_Float16)g.av[j]; }
    #pragma unroll
    for (int ct = 0; ct < 4; ++ct) {
        f16x4 bF;
        #pragma unroll
        for (int j = 0; j < 4; ++j) bF[j] = (_Float16)g.fv[ct][j];
        const f32x4 d = __builtin_amdgcn_mfma_f32_16x16x16f16(aW, bF, z4, 0, 0, 0);
        f16x4 dh;
        #pragma unroll
        for (int r = 0; r < 4; ++r) dh[r] = (_Float16)d[r];
        *(f16x4*)&sProw[(ct * 16 + ml) * 16 + qsw * 4] = dh;
    }
    const f32x4 d = __builtin_amdgcn_mfma_f32_16x16x16f16(aW, bA, z4, 0, 0, 0);
    if (mlo) {
        f16x4 dh;
        #pragma unroll
        for (int r = 0; r < 4; ++r) dh[r] = (_Float16)d[r];
        *(f16x4*)&sProw[(64 + ml) * 16 + qsw * 4] = dh;
    }
}

__global__ void __launch_bounds__(512, 4)
pconv_fallback(const float* __restrict__ inF, const int* __restrict__ inds,
               const float* __restrict__ Wn, const float* __restrict__ addF,
               const _Float16* __restrict__ LWh, const float* __restrict__ bias,
               float* __restrict__ out)
{
    extern __shared__ __align__(16) _Float16 sP[];
    const int t = threadIdx.x, lane = t & 63, w = t >> 6;
    const int q = lane >> 4, ml = lane & 15;
    const bool mlo = (ml < 3);
    const int qsw = q ^ (((ml >> 2) & 1) << 1);
    const int bid = blockIdx.x, b = bid / NBLK;
    const int n0 = (bid - b * NBLK) * 32, bbase = b * NPTS;
    const int ind_lane = inds[(bbase + n0 + w * 4) * 16 + lane];
    sP[(t >> 4) * PSTR + 1072 + (t & 15)] = (_Float16)0.f;

    const int nk0 = (bbase + n0 + w * 4) * 16;
    _Float16* sPw = sP + (w * 4) * PSTR;
    GR32 g0, g1;
    issue_gather32(inF, Wn, addF, bbase, nk0,      ind_lane, 0, q, ml, mlo, g0);
    issue_gather32(inF, Wn, addF, bbase, nk0 + 16, ind_lane, 1, q, ml, mlo, g1);
    compute_point32(g0, sPw,            qsw, ml, mlo);
    issue_gather32(inF, Wn, addF, bbase, nk0 + 32, ind_lane, 2, q, ml, mlo, g0);
    compute_point32(g1, sPw + PSTR,     qsw, ml, mlo);
    issue_gather32(inF, Wn, addF, bbase, nk0 + 48, ind_lane, 3, q, ml, mlo, g1);
    compute_point32(g0, sPw + 2 * PSTR, qsw, ml, mlo);
    compute_point32(g1, sPw + 3 * PSTR, qsw, ml, mlo);

    const int o0 = w * 16;
    const _Float16* bP = LWh + (o0 + ml) * 32 + q * 8;
    f16x8 bcur = *(const f16x8*)(bP);
    f16x8 bnxt = *(const f16x8*)(bP + 4096);
    __syncthreads();

    const float bz = bias[o0 + ml];
    f32x4 acc0 = {0.f, 0.f, 0.f, 0.f};
    f32x4 acc1 = {0.f, 0.f, 0.f, 0.f};
    const _Float16* aP0 = sP + ml * PSTR + (q >> 1) * 16 + (q & 1) * 8;
    const _Float16* aP1 = aP0 + 16 * PSTR;
    const int flip = (q & 1) ? -8 : 8;
    #pragma unroll 2
    for (int ch = 0; ch < 34; ++ch) {
        const int chf = (ch + 2 < 34) ? (ch + 2) : 33;
        f16x8 bfut = *(const f16x8*)(bP + chf * 4096);
        const int off = ch * 32 + ((ch & 2) ? flip : 0);
        f16x8 a0 = *(const f16x8*)(aP0 + off);
        f16x8 a1 = *(const f16x8*)(aP1 + off);
        acc0 = __builtin_amdgcn_mfma_f32_16x16x32_f16(a0, bcur, acc0, 0, 0, 0);
        acc1 = __builtin_amdgcn_mfma_f32_16x16x32_f16(a1, bcur, acc1, 0, 0, 0);
        bcur = bnxt; bnxt = bfut;
    }
    float* ob = out + (bbase + n0 + q * 4) * 128 + o0 + ml;
    #pragma unroll
    for (int r = 0; r < 4; ++r) ob[r * 128] = acc0[r] + bz;
    ob += 16 * 128;
    #pragma unroll
    for (int r = 0; r < 4; ++r) ob[r * 128] = acc1[r] + bz;
}

extern "C" void kernel_launch(void* const* d_in, const int* in_sizes, int n_in,
                              void* d_out, int out_size, void* d_ws, size_t ws_size,
                              hipStream_t stream)
{
    const float* inF  = (const float*)d_in[0];
    const int*   inds = (const int*)  d_in[1];
    const float* Wn   = (const float*)d_in[2];
    const float* addF = (const float*)d_in[3];
    const float* LW   = (const float*)d_in[4];
    const float* bias = (const float*)d_in[5];
    float* out = (float*)d_out;
    _Float16* LWh = (_Float16*)d_ws;

    const bool f16p = (ws_size >= (size_t)WS_NEED);

    hipFuncSetAttribute((const void*)pconv_persistent,
                        hipFuncAttributeMaxDynamicSharedMemorySize, SPBYTES);
    hipFuncSetAttribute((const void*)pconv_fallback,
                        hipFuncAttributeMaxDynamicSharedMemorySize, SPBYTES_FB);

    cvt_lw_kernel<<<dim3(128), dim3(256), 0, stream>>>(LW, LWh);
    if (f16p) {
        _Float16* inF16 = (_Float16*)((char*)d_ws + LWH_BYTES);
        cvt_inf_kernel<<<dim3((2 * NPTS * 64 + 255) / 256), dim3(256), 0, stream>>>(
            inF, inF16);
        pconv_persistent<<<dim3(NBLOCKS), dim3(512), SPBYTES, stream>>>(
            inF16, inds, Wn, addF, LWh, bias, out);
    } else {
        pconv_fallback<<<dim3(2 * NBLK), dim3(512), SPBYTES_FB, stream>>>(
            inF, inds, Wn, addF, LWh, bias, out);
    }
}